// Round 1
// 6624.725 us; speedup vs baseline: 1.2069x; 1.2069x over previous
//
#include <hip/hip_runtime.h>
#include <math.h>

typedef unsigned short u16;
typedef __attribute__((ext_vector_type(8))) short bf16x8;
typedef __attribute__((ext_vector_type(4))) float f32x4;

#define AS1 __attribute__((address_space(1)))
#define AS3 __attribute__((address_space(3)))

// async global->LDS, 16B per lane; lds dest is wave-uniform base + lane*16
__device__ __forceinline__ void gll16(const u16* g, u16* l) {
  __builtin_amdgcn_global_load_lds((const AS1 void*)g, (AS3 void*)l, 16, 0, 0);
}

__device__ __forceinline__ u16 f2bf(float f) {
  union { float f; unsigned u; } v; v.f = f;
  unsigned r = (v.u + 0x7FFFu + ((v.u >> 16) & 1u)) >> 16;
  return (u16)r;
}

__device__ __forceinline__ float bf2f(u16 h) {
  union { unsigned u; float f; } v; v.u = ((unsigned)h) << 16;
  return v.f;
}

// ---------------------------------------------------------------------------
// elementwise f32 -> bf16 convert (grid-stride)
// ---------------------------------------------------------------------------
__global__ __launch_bounds__(256) void f32_to_bf16(const float* __restrict__ src,
                                                   u16* __restrict__ dst, int n) {
  int i = blockIdx.x * 256 + threadIdx.x;
  int stride = gridDim.x * 256;
  for (; i < n; i += stride) dst[i] = f2bf(src[i]);
}

// hidden -> bf16 h_init, and zero the 512 step flags
__global__ __launch_bounds__(256) void prep_h_flags(const float* __restrict__ hidden,
                                                    u16* __restrict__ h_init,
                                                    unsigned* __restrict__ flags) {
  int i = blockIdx.x * 256 + threadIdx.x;
  if (i < 32768) h_init[i] = f2bf(hidden[i]);
  if (i < 512) flags[i] = 0u;
}

// ---------------------------------------------------------------------------
// m97-style bf16 GEMM, C = A * B^T  (A: MxK bf16, B: NxK bf16, C: MxN fp32)
// tile 128x128, BK=32, 4 waves in 2x2, each wave 64x64 via 4x4 16x16x32 MFMA
// M, N multiples of 128; K multiple of 32.
// ---------------------------------------------------------------------------
__global__ __launch_bounds__(256) void gemm_bt(const u16* __restrict__ A,
                                               const u16* __restrict__ B,
                                               float* __restrict__ C,
                                               int M, int N, int K) {
  __shared__ u16 As[128 * 32];   // row-major [128][32]
  __shared__ u16 Bs[128 * 32];
  const int tid  = threadIdx.x;
  const int lane = tid & 63;
  const int wv   = tid >> 6;
  const int quad = lane >> 4;
  const int r16  = lane & 15;
  const int wm   = wv >> 1, wn = wv & 1;
  const int tm   = blockIdx.y, tn = blockIdx.x;
  const int rA   = lane >> 2;        // 0..15 (row within 16-row staging group)
  const int cA   = (lane & 3) * 8;   // k granule

  f32x4 acc[4][4] = {};
  const size_t Abase = (size_t)(tm * 128) * K;
  const size_t Bbase = (size_t)(tn * 128) * K;

  for (int k0 = 0; k0 < K; k0 += 32) {
#pragma unroll
    for (int q = 0; q < 2; ++q) {
      int r = wv * 32 + q * 16 + rA;
      gll16(A + Abase + (size_t)r * K + k0 + cA, &As[wv * 1024 + q * 512]);
      gll16(B + Bbase + (size_t)r * K + k0 + cA, &Bs[wv * 1024 + q * 512]);
    }
    __syncthreads();
    bf16x8 af[4], bfr[4];
#pragma unroll
    for (int i = 0; i < 4; ++i) {
      af[i]  = *(const bf16x8*)&As[(wm * 64 + i * 16 + r16) * 32 + quad * 8];
      bfr[i] = *(const bf16x8*)&Bs[(wn * 64 + i * 16 + r16) * 32 + quad * 8];
    }
#pragma unroll
    for (int i = 0; i < 4; ++i)
#pragma unroll
      for (int j = 0; j < 4; ++j)
        acc[i][j] = __builtin_amdgcn_mfma_f32_16x16x32_bf16(af[i], bfr[j], acc[i][j], 0, 0, 0);
    __syncthreads();
  }
  // C/D layout: col = lane&15, row = quad*4 + reg  (m89/m91-verified)
#pragma unroll
  for (int i = 0; i < 4; ++i) {
    int row = tm * 128 + wm * 64 + i * 16 + quad * 4;
#pragma unroll
    for (int j = 0; j < 4; ++j) {
      int col = tn * 128 + wn * 64 + j * 16 + r16;
#pragma unroll
      for (int r = 0; r < 4; ++r)
        C[(size_t)(row + r) * N + col] = acc[i][j][r];
    }
  }
}

// ---------------------------------------------------------------------------
// Persistent RNN scan: all 512 steps in ONE kernel.
// 32 blocks x 256 threads; block i owns output columns [32*i, 32*i+32).
// Each wave (2x2 over batch-halves x col-halves) computes one 16x16 tile
// per step: h_t = tanh(T[x[:,t]] + h_{t-1} @ Wh^T), written bf16 to out_bf.
// Wh rows for the wave's 16 columns live in REGISTERS for the whole scan
// (16x1024 bf16 = 128 VGPR/AGPR; 1 wave/SIMD so budget is 512).
// Cross-block step handoff: per-step flag, agent-scope atomics + threadfence
// (sc1 writeback/invalidate handles cross-XCD L2 non-coherence).
// ---------------------------------------------------------------------------
#define NBLK 32

__global__ __launch_bounds__(256, 1) void rnn_scan(const u16* __restrict__ h_init,
                                                   const u16* __restrict__ Whb,
                                                   const float* __restrict__ T,
                                                   const int* __restrict__ x,
                                                   u16* __restrict__ out_bf,
                                                   unsigned* __restrict__ flags) {
  const int tid  = threadIdx.x;
  const int lane = tid & 63;
  const int wv   = tid >> 6;
  const int quad = lane >> 4;
  const int r16  = lane & 15;
  const int wm   = wv >> 1, wn = wv & 1;
  const int n0   = blockIdx.x * 32;
  const int n    = n0 + wn * 16 + r16;   // output column (and Wh row) for B-frag/epilogue
  const int bA   = wm * 16 + r16;        // batch row this lane loads for the A-frag

  // Pin this wave's 16 Wh rows in registers: wr[kk] covers k = kk*32 + quad*8 .. +8
  bf16x8 wr[32];
  {
    const u16* wp = Whb + (size_t)n * 1024 + quad * 8;
#pragma unroll
    for (int kk = 0; kk < 32; ++kk) wr[kk] = *(const bf16x8*)(wp + kk * 32);
  }

#pragma unroll 1
  for (int t = 0; t < 512; ++t) {
    // ---- prefetch T-gather and x (independent of h_{t-1}) ----
    int idxs[4];
#pragma unroll
    for (int r = 0; r < 4; ++r) {
      int b = wm * 16 + quad * 4 + r;
      idxs[r] = x[b * 512 + t];
    }
    float tv[4];
#pragma unroll
    for (int r = 0; r < 4; ++r) tv[r] = T[(size_t)idxs[r] * 1024 + n];

    // ---- wait for step t-1 from all blocks ----
    const u16* hprev;
    size_t astr;
    if (t == 0) {
      hprev = h_init; astr = 1024;
    } else {
      hprev = out_bf + (size_t)(t - 1) * 1024; astr = (size_t)512 * 1024;
      if (tid == 0) {
        while (__hip_atomic_load(&flags[t - 1], __ATOMIC_RELAXED,
                                 __HIP_MEMORY_SCOPE_AGENT) < NBLK) {
          __builtin_amdgcn_s_sleep(1);
        }
      }
      __syncthreads();
      __threadfence();   // acquire: invalidate stale L1/L2 before reading remote h
    }

    // ---- load all 32 A-fragments up front (one exposed latency) ----
    const u16* ap = hprev + (size_t)bA * astr + quad * 8;
    bf16x8 a[32];
#pragma unroll
    for (int kk = 0; kk < 32; ++kk) a[kk] = *(const bf16x8*)(ap + (size_t)kk * 32);

    // ---- 32 MFMAs on 4 interleaved accumulators (dep distance 4) ----
    f32x4 acc[4] = {};
#pragma unroll
    for (int kk = 0; kk < 32; ++kk)
      acc[kk & 3] = __builtin_amdgcn_mfma_f32_16x16x32_bf16(a[kk], wr[kk], acc[kk & 3], 0, 0, 0);

    // ---- epilogue: + T gather, tanh, bf16 store ----
    // C/D layout: col = lane&15 (-> n), row = quad*4 + reg (-> batch)
#pragma unroll
    for (int r = 0; r < 4; ++r) {
      int b = wm * 16 + quad * 4 + r;
      float v = acc[0][r] + acc[1][r] + acc[2][r] + acc[3][r] + tv[r];
      out_bf[((size_t)b * 512 + t) * 1024 + n] = f2bf(tanhf(v));
    }

    __threadfence();   // release: make h_t visible device-wide
    __syncthreads();
    if (tid == 0)
      __hip_atomic_fetch_add(&flags[t], 1u, __ATOMIC_RELAXED, __HIP_MEMORY_SCOPE_AGENT);
  }
}

// ---------------------------------------------------------------------------
// final hidden: bf16 row (b*512+511) of outputs -> fp32 tail of d_out
// ---------------------------------------------------------------------------
__global__ __launch_bounds__(256) void finalize_hidden(const u16* __restrict__ ob,
                                                       float* __restrict__ dst) {
  int i = blockIdx.x * 256 + threadIdx.x;   // 0..32767
  int b = i >> 10, j = i & 1023;
  dst[i] = bf2f(ob[((size_t)(b * 512 + 511)) * 1024 + j]);
}

// ---------------------------------------------------------------------------
extern "C" void kernel_launch(void* const* d_in, const int* in_sizes, int n_in,
                              void* d_out, int out_size, void* d_ws, size_t ws_size,
                              hipStream_t stream) {
  const int*   x      = (const int*)d_in[0];    // [32][512]
  const float* hidden = (const float*)d_in[1];  // [32][1024]
  const float* emb    = (const float*)d_in[2];  // [8192][1024]
  const float* Wh     = (const float*)d_in[3];  // [1024][1024]
  const float* We     = (const float*)d_in[4];  // [1024][1024]
  const float* Wo     = (const float*)d_in[5];  // [8192][1024]
  float* out = (float*)d_out;                   // logits [32][512][8192] ++ hidden [32][1024]

  char* ws = (char*)d_ws;
  u16*   emb_bf = (u16*)(ws);                   // 16,777,216 B
  u16*   Wo_bf  = (u16*)(ws + 16777216);        // 16,777,216 B
  u16*   We_bf  = (u16*)(ws + 33554432);        //  2,097,152 B
  u16*   Wh_bf  = (u16*)(ws + 35651584);        //  2,097,152 B
  float* T      = (float*)(ws + 37748736);      // 33,554,432 B  (emb @ We^T, fp32)
  u16*   out_bf = (u16*)(ws + 71303168);        // 33,554,432 B  (h_t rows, bf16)
  u16*   h_init = (u16*)(ws + 104857600);       //     65,536 B
  // total 104,923,136 B

  // step flags live at the head of the logits region (fully overwritten by the
  // final GEMM), so workspace layout is unchanged.
  unsigned* flags = (unsigned*)d_out;

  // bf16 conversions
  hipLaunchKernelGGL(f32_to_bf16, dim3(2048), dim3(256), 0, stream, emb, emb_bf, 8388608);
  hipLaunchKernelGGL(f32_to_bf16, dim3(2048), dim3(256), 0, stream, Wo, Wo_bf, 8388608);
  hipLaunchKernelGGL(f32_to_bf16, dim3(512),  dim3(256), 0, stream, We, We_bf, 1048576);
  hipLaunchKernelGGL(f32_to_bf16, dim3(512),  dim3(256), 0, stream, Wh, Wh_bf, 1048576);
  hipLaunchKernelGGL(prep_h_flags, dim3(128), dim3(256), 0, stream, hidden, h_init, flags);

  // T = emb @ We^T : M=8192, N=1024, K=1024
  hipLaunchKernelGGL(gemm_bt, dim3(1024 / 128, 8192 / 128), dim3(256), 0, stream,
                     emb_bf, We_bf, T, 8192, 1024, 1024);

  // persistent scan: 512 steps in one kernel, 32 co-resident blocks
  hipLaunchKernelGGL(rnn_scan, dim3(NBLK), dim3(256), 0, stream,
                     h_init, Wh_bf, T, x, out_bf, flags);

  // logits = outputs @ Wo^T : M=16384, N=8192, K=1024 -> straight into d_out
  hipLaunchKernelGGL(gemm_bt, dim3(8192 / 128, 16384 / 128), dim3(256), 0, stream,
                     out_bf, Wo_bf, out, 16384, 8192, 1024);

  // final hidden tail
  hipLaunchKernelGGL(finalize_hidden, dim3(128), dim3(256), 0, stream,
                     out_bf, out + 134217728);
}